// Round 1
// baseline (1404.965 us; speedup 1.0000x reference)
//
#include <hip/hip_runtime.h>
#include <hip/hip_bf16.h>
#include <math.h>

#define HCW 512   // concat width H*C
#define NHD 8     // heads
#define CCH 64    // per-head channels

// ---------------- CSR build (by dst) ----------------
__global__ void k_hist(const int* __restrict__ ei, int* __restrict__ deg, int E, int N) {
  int e = blockIdx.x * blockDim.x + threadIdx.x;
  if (e >= E + N) return;
  int dst = (e < E) ? ei[E + e] : (e - E);   // self-loops appended
  atomicAdd(&deg[dst], 1);
}

__global__ __launch_bounds__(1024) void k_scan(const int* __restrict__ deg, int* __restrict__ ptr, int n) {
  __shared__ int sm[1024];
  __shared__ int carry;
  if (threadIdx.x == 0) { carry = 0; ptr[0] = 0; }
  __syncthreads();
  for (int base = 0; base < n; base += 1024) {
    int i = base + threadIdx.x;
    int v = (i < n) ? deg[i] : 0;
    sm[threadIdx.x] = v;
    __syncthreads();
    for (int off = 1; off < 1024; off <<= 1) {
      int t = (threadIdx.x >= off) ? sm[threadIdx.x - off] : 0;
      __syncthreads();
      sm[threadIdx.x] += t;
      __syncthreads();
    }
    if (i < n) ptr[i + 1] = carry + sm[threadIdx.x];
    __syncthreads();
    if (threadIdx.x == 0) carry += sm[1023];
    __syncthreads();
  }
}

__global__ void k_fill(const int* __restrict__ ei, const int* __restrict__ ptr,
                       int* __restrict__ cnt, int* __restrict__ csr_src, int E, int N) {
  int e = blockIdx.x * blockDim.x + threadIdx.x;
  if (e >= E + N) return;
  int src, dst;
  if (e < E) { src = ei[e]; dst = ei[E + e]; } else { src = e - E; dst = e - E; }
  int pos = ptr[dst] + atomicAdd(&cnt[dst], 1);
  csr_src[pos] = src;
}

// ---------------- input projection: h = relu(x @ W_in + b_in) ----------------
__global__ __launch_bounds__(256) void k_inproj(const float* __restrict__ x, const float* __restrict__ W,
                                                const float* __restrict__ b, float* __restrict__ h, int N) {
  int n = blockIdx.x >> 1;
  if (n >= N) return;
  int j = ((blockIdx.x & 1) << 8) + threadIdx.x;
  const float* xr = x + (size_t)n * 32;
  float acc = b[j];
  #pragma unroll
  for (int k = 0; k < 32; k++) acc += xr[k] * W[k * HCW + j];
  h[(size_t)n * HCW + j] = fmaxf(acc, 0.f);
}

// ---------------- fp32 GEMM: C[M,512] = A[M,512] @ B[512,512] ----------------
__global__ __launch_bounds__(256) void k_gemm(const float* __restrict__ A, const float* __restrict__ B,
                                              float* __restrict__ C, int M) {
  __shared__ float As[16][68];
  __shared__ float Bs[16][68];
  int bm = blockIdx.y * 64, bn = blockIdx.x * 64;
  int t = threadIdx.x;
  int tx = t & 15, ty = t >> 4;
  int arow = t >> 2, acol4 = (t & 3) << 2;
  int brow = t >> 4, bcol4 = (t & 15) << 2;
  float acc[4][4] = {};
  for (int k0 = 0; k0 < 512; k0 += 16) {
    int gm = bm + arow;
    float4 av = make_float4(0.f, 0.f, 0.f, 0.f);
    if (gm < M) av = *(const float4*)(A + (size_t)gm * 512 + k0 + acol4);
    As[acol4 + 0][arow] = av.x;
    As[acol4 + 1][arow] = av.y;
    As[acol4 + 2][arow] = av.z;
    As[acol4 + 3][arow] = av.w;
    float4 bv = *(const float4*)(B + (size_t)(k0 + brow) * 512 + bn + bcol4);
    *(float4*)&Bs[brow][bcol4] = bv;
    __syncthreads();
    #pragma unroll
    for (int kk = 0; kk < 16; kk++) {
      float4 a4 = *(const float4*)&As[kk][ty * 4];
      float4 b4 = *(const float4*)&Bs[kk][tx * 4];
      float a[4] = {a4.x, a4.y, a4.z, a4.w};
      float b[4] = {b4.x, b4.y, b4.z, b4.w};
      #pragma unroll
      for (int i = 0; i < 4; i++)
        #pragma unroll
        for (int j = 0; j < 4; j++) acc[i][j] += a[i] * b[j];
    }
    __syncthreads();
  }
  #pragma unroll
  for (int i = 0; i < 4; i++) {
    int gm = bm + ty * 4 + i;
    if (gm < M) {
      float4 o = make_float4(acc[i][0], acc[i][1], acc[i][2], acc[i][3]);
      *(float4*)(C + (size_t)gm * 512 + bn + tx * 4) = o;
    }
  }
}

// ---------------- per-node s/d: s[n][h] = sum_c hp[n][h*64+c]*att_src[h][c] ----------------
__global__ __launch_bounds__(256) void k_sd(const float* __restrict__ hp, const float* __restrict__ a_src,
                                            const float* __restrict__ a_dst, float* __restrict__ s,
                                            float* __restrict__ d, int N) {
  int wave = threadIdx.x >> 6, lane = threadIdx.x & 63;
  int n = blockIdx.x * 4 + wave;
  if (n >= N) return;
  const float* row = hp + (size_t)n * HCW;
  int head = lane >> 3, c0 = lane & 7;
  float ps = 0.f, pd = 0.f;
  #pragma unroll
  for (int tt = 0; tt < 8; tt++) {
    int c = c0 + tt * 8;
    float hv = row[head * 64 + c];
    ps += hv * a_src[head * 64 + c];
    pd += hv * a_dst[head * 64 + c];
  }
  ps += __shfl_xor(ps, 1); pd += __shfl_xor(pd, 1);
  ps += __shfl_xor(ps, 2); pd += __shfl_xor(pd, 2);
  ps += __shfl_xor(ps, 4); pd += __shfl_xor(pd, 4);
  if (c0 == 0) { s[(size_t)n * NHD + head] = ps; d[(size_t)n * NHD + head] = pd; }
}

// ---------------- per-dst segment softmax (unnormalized exp + denom) ----------------
__global__ __launch_bounds__(64) void k_softmax(const int* __restrict__ ptr, const int* __restrict__ csr_src,
                                                const float* __restrict__ s, const float* __restrict__ d,
                                                float* __restrict__ exb, float* __restrict__ den) {
  int n = blockIdx.x;
  int lane = threadIdx.x;
  int head = lane & 7, slot = lane >> 3;
  int beg = ptr[n], end = ptr[n + 1];
  float dn = d[(size_t)n * NHD + head];
  float mx = -1e30f;
  for (int i = beg + slot; i < end; i += 8) {
    float e = s[(size_t)csr_src[i] * NHD + head] + dn;
    e = (e > 0.f) ? e : 0.2f * e;
    mx = fmaxf(mx, e);
  }
  mx = fmaxf(mx, __shfl_xor(mx, 8));
  mx = fmaxf(mx, __shfl_xor(mx, 16));
  mx = fmaxf(mx, __shfl_xor(mx, 32));
  float sum = 0.f;
  for (int i = beg + slot; i < end; i += 8) {
    float e = s[(size_t)csr_src[i] * NHD + head] + dn;
    e = (e > 0.f) ? e : 0.2f * e;
    float ex = __expf(e - mx);
    exb[(size_t)i * NHD + head] = ex;
    sum += ex;
  }
  sum += __shfl_xor(sum, 8);
  sum += __shfl_xor(sum, 16);
  sum += __shfl_xor(sum, 32);
  if (slot == 0) den[(size_t)n * NHD + head] = sum;
}

// ---------------- aggregation: h_out[n] = relu( (sum_e exb*hp[src]) / den + bias ) ----------------
__global__ __launch_bounds__(256) void k_agg(const int* __restrict__ ptr, const int* __restrict__ csr_src,
                                             const float* __restrict__ hp, const float* __restrict__ exb,
                                             const float* __restrict__ den, const float* __restrict__ bias,
                                             float* __restrict__ hout) {
  int n = blockIdx.x;
  int t = threadIdx.x;
  int c0 = t, c1 = t + 256;
  int h0 = c0 >> 6, h1 = c1 >> 6;
  int beg = ptr[n], end = ptr[n + 1];
  float acc0 = 0.f, acc1 = 0.f;
  for (int i = beg; i < end; i++) {
    int src = csr_src[i];
    const float* row = hp + (size_t)src * HCW;
    float e0 = exb[(size_t)i * NHD + h0];
    float e1 = exb[(size_t)i * NHD + h1];
    acc0 += e0 * row[c0];
    acc1 += e1 * row[c1];
  }
  float inv0 = 1.f / (den[(size_t)n * NHD + h0] + 1e-16f);
  float inv1 = 1.f / (den[(size_t)n * NHD + h1] + 1e-16f);
  acc0 = acc0 * inv0 + bias[c0];
  acc1 = acc1 * inv1 + bias[c1];
  hout[(size_t)n * HCW + c0] = fmaxf(acc0, 0.f);
  hout[(size_t)n * HCW + c1] = fmaxf(acc1, 0.f);
}

// ---------------- final heads ----------------
__global__ __launch_bounds__(256) void k_final(const float* __restrict__ h,
                                               const float* __restrict__ W_att, const float* __restrict__ b_att,
                                               const float* __restrict__ W_h1, const float* __restrict__ b_h1,
                                               const float* __restrict__ W_h2, const float* __restrict__ b_h2,
                                               float* __restrict__ anomaly, float* __restrict__ attw, int N) {
  __shared__ float sh[4][512];
  int wave = threadIdx.x >> 6, lane = threadIdx.x & 63;
  int n = blockIdx.x * 4 + wave;
  bool active = (n < N);
  if (active) {
    const float* row = h + (size_t)n * HCW;
    #pragma unroll
    for (int i = 0; i < 8; i++) sh[wave][i * 64 + lane] = row[i * 64 + lane];
  }
  __syncthreads();
  if (!active) return;
  // attention head: logits = h @ W_att + b_att, softmax over 8
  float acc[8] = {0.f, 0.f, 0.f, 0.f, 0.f, 0.f, 0.f, 0.f};
  #pragma unroll
  for (int i = 0; i < 8; i++) {
    int k = i * 64 + lane;
    float hv = sh[wave][k];
    #pragma unroll
    for (int j = 0; j < 8; j++) acc[j] += hv * W_att[k * 8 + j];
  }
  #pragma unroll
  for (int j = 0; j < 8; j++) {
    #pragma unroll
    for (int m = 1; m < 64; m <<= 1) acc[j] += __shfl_xor(acc[j], m);
    acc[j] += b_att[j];
  }
  float mx = acc[0];
  #pragma unroll
  for (int j = 1; j < 8; j++) mx = fmaxf(mx, acc[j]);
  float sum = 0.f;
  float ex[8];
  #pragma unroll
  for (int j = 0; j < 8; j++) { ex[j] = __expf(acc[j] - mx); sum += ex[j]; }
  if (lane < 8) attw[(size_t)n * 8 + lane] = ex[lane] / sum;
  // anomaly head: sigmoid(relu(h@W_h1+b_h1)@W_h2 + b_h2)
  float tacc = b_h1[lane];
  for (int k = 0; k < 512; k++) tacc += sh[wave][k] * W_h1[k * 64 + lane];
  tacc = fmaxf(tacc, 0.f);
  float p = tacc * W_h2[lane];
  #pragma unroll
  for (int m = 1; m < 64; m <<= 1) p += __shfl_xor(p, m);
  if (lane == 0) anomaly[n] = 1.f / (1.f + __expf(-(p + b_h2[0])));
}

extern "C" void kernel_launch(void* const* d_in, const int* in_sizes, int n_in,
                              void* d_out, int out_size, void* d_ws, size_t ws_size,
                              hipStream_t stream) {
  const float* x       = (const float*)d_in[0];
  const int*   ei      = (const int*)d_in[1];
  const float* W_in    = (const float*)d_in[2];
  const float* b_in    = (const float*)d_in[3];
  const float* W_gat   = (const float*)d_in[4];
  const float* att_src = (const float*)d_in[5];
  const float* att_dst = (const float*)d_in[6];
  const float* b_gat   = (const float*)d_in[7];
  const float* W_att   = (const float*)d_in[8];
  const float* b_att   = (const float*)d_in[9];
  const float* W_h1    = (const float*)d_in[10];
  const float* b_h1    = (const float*)d_in[11];
  const float* W_h2    = (const float*)d_in[12];
  const float* b_h2    = (const float*)d_in[13];

  const int N  = in_sizes[0] / 32;   // 30000
  const int E  = in_sizes[1] / 2;    // 480000
  const int ET = E + N;              // with self-loops

  char* ws = (char*)d_ws;
  size_t off = 0;
  auto alloc = [&](size_t bytes) -> void* {
    void* p = ws + off;
    off = (off + bytes + 255) & ~(size_t)255;
    return p;
  };
  float* h    = (float*)alloc((size_t)N * HCW * 4);
  float* hp   = (float*)alloc((size_t)N * HCW * 4);
  float* exb  = (float*)alloc((size_t)ET * NHD * 4);
  float* sarr = (float*)alloc((size_t)N * NHD * 4);
  float* darr = (float*)alloc((size_t)N * NHD * 4);
  float* den  = (float*)alloc((size_t)N * NHD * 4);
  int* deg    = (int*)alloc((size_t)N * 4);
  int* ptr    = (int*)alloc((size_t)(N + 1) * 4);
  int* cnt    = (int*)alloc((size_t)N * 4);
  int* csr    = (int*)alloc((size_t)ET * 4);

  float* anomaly = (float*)d_out;
  float* attw    = (float*)d_out + N;

  hipMemsetAsync(deg, 0, (size_t)N * 4, stream);
  hipMemsetAsync(cnt, 0, (size_t)N * 4, stream);

  int gbE = (ET + 255) / 256;
  k_hist<<<gbE, 256, 0, stream>>>(ei, deg, E, N);
  k_scan<<<1, 1024, 0, stream>>>(deg, ptr, N);
  k_fill<<<gbE, 256, 0, stream>>>(ei, ptr, cnt, csr, E, N);

  k_inproj<<<N * 2, 256, 0, stream>>>(x, W_in, b_in, h, N);

  dim3 ggrid(512 / 64, (N + 63) / 64);
  for (int l = 0; l < 3; l++) {
    k_gemm<<<ggrid, 256, 0, stream>>>(h, W_gat + (size_t)l * HCW * HCW, hp, N);
    k_sd<<<(N + 3) / 4, 256, 0, stream>>>(hp, att_src + (size_t)l * NHD * CCH,
                                          att_dst + (size_t)l * NHD * CCH, sarr, darr, N);
    k_softmax<<<N, 64, 0, stream>>>(ptr, csr, sarr, darr, exb, den);
    k_agg<<<N, 256, 0, stream>>>(ptr, csr, hp, exb, den, b_gat + (size_t)l * HCW, h);
  }

  k_final<<<(N + 3) / 4, 256, 0, stream>>>(h, W_att, b_att, W_h1, b_h1, W_h2, b_h2,
                                           anomaly, attw, N);
}

// Round 2
// 760.266 us; speedup vs baseline: 1.8480x; 1.8480x over previous
//
#include <hip/hip_runtime.h>
#include <hip/hip_bf16.h>
#include <math.h>

#define HCW 512   // concat width H*C
#define NHD 8     // heads
#define CCH 64    // per-head channels

typedef unsigned short u16;
typedef unsigned int   u32;
typedef __attribute__((ext_vector_type(8))) short bf16x8;
typedef __attribute__((ext_vector_type(4))) float f32x4;

__device__ __forceinline__ float bf2f(u32 u) {
  union { float f; u32 i; } v; v.i = u << 16; return v.f;
}
__device__ __forceinline__ u16 f2bf(float f) {
  u32 x = __builtin_bit_cast(u32, f);
  return (u16)((x + 0x7fff + ((x >> 16) & 1)) >> 16);
}
__device__ __forceinline__ void gload_lds16(const void* g, void* l) {
  __builtin_amdgcn_global_load_lds(
      (const __attribute__((address_space(1))) u32*)g,
      (__attribute__((address_space(3))) u32*)l, 16, 0, 0);
}

// ---------------- CSR build (by dst) ----------------
__global__ void k_hist(const int* __restrict__ ei, int* __restrict__ deg, int E, int N) {
  int e = blockIdx.x * blockDim.x + threadIdx.x;
  if (e >= E + N) return;
  int dst = (e < E) ? ei[E + e] : (e - E);   // self-loops appended
  atomicAdd(&deg[dst], 1);
}

__global__ __launch_bounds__(256) void k_scan1(const int* __restrict__ deg, int* __restrict__ ptr,
                                               int* __restrict__ bsum, int n) {
  __shared__ int sm[256];
  int b = blockIdx.x, i = b * 256 + threadIdx.x;
  int v = (i < n) ? deg[i] : 0;
  sm[threadIdx.x] = v;
  __syncthreads();
  for (int off = 1; off < 256; off <<= 1) {
    int t = (threadIdx.x >= off) ? sm[threadIdx.x - off] : 0;
    __syncthreads();
    sm[threadIdx.x] += t;
    __syncthreads();
  }
  if (i < n) ptr[i + 1] = sm[threadIdx.x];
  if (threadIdx.x == 255) bsum[b] = sm[255];
}

__global__ __launch_bounds__(256) void k_scan2(const int* __restrict__ bsum, int* __restrict__ boff, int nb) {
  __shared__ int sm[256];
  int v = (threadIdx.x < nb) ? bsum[threadIdx.x] : 0;
  sm[threadIdx.x] = v;
  __syncthreads();
  for (int off = 1; off < 256; off <<= 1) {
    int t = (threadIdx.x >= off) ? sm[threadIdx.x - off] : 0;
    __syncthreads();
    sm[threadIdx.x] += t;
    __syncthreads();
  }
  if (threadIdx.x < nb) boff[threadIdx.x] = sm[threadIdx.x] - v;  // exclusive
}

__global__ __launch_bounds__(256) void k_scan3(int* __restrict__ ptr, const int* __restrict__ boff, int n) {
  int i = blockIdx.x * 256 + threadIdx.x;
  if (i == 0) ptr[0] = 0;
  if (i < n) ptr[i + 1] += boff[blockIdx.x];
}

__global__ void k_fill(const int* __restrict__ ei, const int* __restrict__ ptr,
                       int* __restrict__ cnt, int* __restrict__ csr_src, int E, int N) {
  int e = blockIdx.x * blockDim.x + threadIdx.x;
  if (e >= E + N) return;
  int src, dst;
  if (e < E) { src = ei[e]; dst = ei[E + e]; } else { src = e - E; dst = e - E; }
  int pos = ptr[dst] + atomicAdd(&cnt[dst], 1);
  csr_src[pos] = src;
}

// ---------------- W_gat -> bf16 transposed: Wt[l][n][k] ----------------
__global__ __launch_bounds__(256) void k_wconv(const float* __restrict__ W, u16* __restrict__ Wt) {
  __shared__ float sm[32][33];
  int l = blockIdx.z;
  int k0 = blockIdx.y * 32, n0 = blockIdx.x * 32;
  const float* Wl = W + (size_t)l * HCW * HCW;
  u16* Wtl = Wt + (size_t)l * HCW * HCW;
  int tx = threadIdx.x & 31, ty = threadIdx.x >> 5;  // 8 rows per pass
  #pragma unroll
  for (int r = 0; r < 32; r += 8)
    sm[ty + r][tx] = Wl[(size_t)(k0 + ty + r) * HCW + n0 + tx];
  __syncthreads();
  #pragma unroll
  for (int r = 0; r < 32; r += 8)
    Wtl[(size_t)(n0 + ty + r) * HCW + k0 + tx] = f2bf(sm[tx][ty + r]);
}

// ---------------- input projection: h = relu(x @ W_in + b_in) -> bf16 ----------------
__global__ __launch_bounds__(256) void k_inproj(const float* __restrict__ x, const float* __restrict__ W,
                                                const float* __restrict__ b, u16* __restrict__ h, int N) {
  int n = blockIdx.x >> 1;
  if (n >= N) return;
  int j = ((blockIdx.x & 1) << 8) + threadIdx.x;
  const float* xr = x + (size_t)n * 32;
  float acc = b[j];
  #pragma unroll
  for (int k = 0; k < 32; k++) acc += xr[k] * W[k * HCW + j];
  h[(size_t)n * HCW + j] = f2bf(fmaxf(acc, 0.f));
}

// ---------------- bf16 MFMA GEMM: hp[M,512] = h[M,512] @ W  (B given transposed) ----------------
__global__ __launch_bounds__(256) void k_gemm_mfma(const u16* __restrict__ A,   // [M,512] bf16
                                                   const u16* __restrict__ Bt,  // [512,512] bf16, n-major
                                                   u16* __restrict__ C, int M) {
  __shared__ u16 As[128 * 64];
  __shared__ u16 Bs[128 * 64];
  int tid = threadIdx.x;
  int lane = tid & 63, w = tid >> 6;
  int wr = w >> 1, wc = w & 1;
  int bm = blockIdx.y * 128, bn = blockIdx.x * 128;
  f32x4 acc[4][4] = {};
  for (int k0 = 0; k0 < 512; k0 += 64) {
    __syncthreads();   // previous compute done before overwrite
    #pragma unroll
    for (int it = 0; it < 4; it++) {
      int g = it * 256 + tid;
      int row = g >> 3;                 // 8 granules (16B) per 64-col row
      int gb = g & 7;
      int gs = gb ^ (row & 7);          // pre-swizzled global source (G21)
      int ar = bm + row; if (ar >= M) ar = M - 1;
      gload_lds16(A + (size_t)ar * HCW + k0 + gs * 8, &As[g * 8]);
      gload_lds16(Bt + (size_t)(bn + row) * HCW + k0 + gs * 8, &Bs[g * 8]);
    }
    __syncthreads();   // drains vmcnt
    #pragma unroll
    for (int ks = 0; ks < 2; ks++) {
      bf16x8 af[4], bfr[4];
      #pragma unroll
      for (int f = 0; f < 4; f++) {
        int rowA = wr * 64 + f * 16 + (lane & 15);
        int gA = ((ks * 4 + (lane >> 4)) ^ (rowA & 7));
        af[f] = *(const bf16x8*)&As[rowA * 64 + gA * 8];
        int rowB = wc * 64 + f * 16 + (lane & 15);
        int gB = ((ks * 4 + (lane >> 4)) ^ (rowB & 7));
        bfr[f] = *(const bf16x8*)&Bs[rowB * 64 + gB * 8];
      }
      #pragma unroll
      for (int i = 0; i < 4; i++)
        #pragma unroll
        for (int j = 0; j < 4; j++)
          acc[i][j] = __builtin_amdgcn_mfma_f32_16x16x32_bf16(af[i], bfr[j], acc[i][j], 0, 0, 0);
    }
  }
  // epilogue: C/D layout col=lane&15, row=(lane>>4)*4+reg (m89)
  int gr_base = bm + wr * 64;
  int gc_base = bn + wc * 64;
  #pragma unroll
  for (int i = 0; i < 4; i++) {
    #pragma unroll
    for (int j = 0; j < 4; j++) {
      int col = gc_base + j * 16 + (lane & 15);
      #pragma unroll
      for (int r = 0; r < 4; r++) {
        int rowg = gr_base + i * 16 + (lane >> 4) * 4 + r;
        if (rowg < M) C[(size_t)rowg * HCW + col] = f2bf(acc[i][j][r]);
      }
    }
  }
}

// ---------------- per-node s/d from bf16 hp ----------------
__global__ __launch_bounds__(256) void k_sd(const u16* __restrict__ hp, const float* __restrict__ a_src,
                                            const float* __restrict__ a_dst, float* __restrict__ s,
                                            float* __restrict__ d, int N) {
  int wave = threadIdx.x >> 6, lane = threadIdx.x & 63;
  int n = blockIdx.x * 4 + wave;
  if (n >= N) return;
  int head = lane >> 3, c0 = lane & 7;
  const u16* row = hp + (size_t)n * HCW + head * 64 + c0 * 8;
  uint4 v = *(const uint4*)row;   // 8 bf16
  u32 vv[4] = {v.x, v.y, v.z, v.w};
  float ps = 0.f, pd = 0.f;
  const float* as = a_src + head * 64 + c0 * 8;
  const float* ad = a_dst + head * 64 + c0 * 8;
  #pragma unroll
  for (int j = 0; j < 4; j++) {
    float lo = bf2f(vv[j] & 0xffff), hi = bf2f(vv[j] >> 16);
    ps += lo * as[2 * j] + hi * as[2 * j + 1];
    pd += lo * ad[2 * j] + hi * ad[2 * j + 1];
  }
  ps += __shfl_xor(ps, 1); pd += __shfl_xor(pd, 1);
  ps += __shfl_xor(ps, 2); pd += __shfl_xor(pd, 2);
  ps += __shfl_xor(ps, 4); pd += __shfl_xor(pd, 4);
  if (c0 == 0) { s[(size_t)n * NHD + head] = ps; d[(size_t)n * NHD + head] = pd; }
}

// ---------------- per-dst segment softmax (unnormalized exp + denom) ----------------
__global__ __launch_bounds__(64) void k_softmax(const int* __restrict__ ptr, const int* __restrict__ csr_src,
                                                const float* __restrict__ s, const float* __restrict__ d,
                                                float* __restrict__ exb, float* __restrict__ den) {
  int n = blockIdx.x;
  int lane = threadIdx.x;
  int head = lane & 7, slot = lane >> 3;
  int beg = ptr[n], end = ptr[n + 1];
  float dn = d[(size_t)n * NHD + head];
  float mx = -1e30f;
  for (int i = beg + slot; i < end; i += 8) {
    float e = s[(size_t)csr_src[i] * NHD + head] + dn;
    e = (e > 0.f) ? e : 0.2f * e;
    mx = fmaxf(mx, e);
  }
  mx = fmaxf(mx, __shfl_xor(mx, 8));
  mx = fmaxf(mx, __shfl_xor(mx, 16));
  mx = fmaxf(mx, __shfl_xor(mx, 32));
  float sum = 0.f;
  for (int i = beg + slot; i < end; i += 8) {
    float e = s[(size_t)csr_src[i] * NHD + head] + dn;
    e = (e > 0.f) ? e : 0.2f * e;
    float ex = __expf(e - mx);
    exb[(size_t)i * NHD + head] = ex;
    sum += ex;
  }
  sum += __shfl_xor(sum, 8);
  sum += __shfl_xor(sum, 16);
  sum += __shfl_xor(sum, 32);
  if (slot == 0) den[(size_t)n * NHD + head] = sum;
}

// ---------------- aggregation: h_out[n] = relu( (sum_e exb*hp[src]) / den + bias ) ----------------
__global__ __launch_bounds__(256) void k_agg(const int* __restrict__ ptr, const int* __restrict__ csr_src,
                                             const u16* __restrict__ hp, const float* __restrict__ exb,
                                             const float* __restrict__ den, const float* __restrict__ bias,
                                             u16* __restrict__ hout) {
  int n = blockIdx.x;
  int t = threadIdx.x;
  int c = t * 2;            // two adjacent channels, same head
  int h = c >> 6;
  int beg = ptr[n], end = ptr[n + 1];
  float acc0 = 0.f, acc1 = 0.f;
  for (int i = beg; i < end; i++) {
    int src = csr_src[i];
    u32 pv = *(const u32*)(hp + (size_t)src * HCW + c);   // 2 bf16
    float e = exb[(size_t)i * NHD + h];
    acc0 += e * bf2f(pv & 0xffff);
    acc1 += e * bf2f(pv >> 16);
  }
  float inv = 1.f / (den[(size_t)n * NHD + h] + 1e-16f);
  acc0 = fmaxf(acc0 * inv + bias[c], 0.f);
  acc1 = fmaxf(acc1 * inv + bias[c + 1], 0.f);
  u32 packed = (u32)f2bf(acc0) | ((u32)f2bf(acc1) << 16);
  *(u32*)(hout + (size_t)n * HCW + c) = packed;
}

// ---------------- final heads (bf16 h in) ----------------
__global__ __launch_bounds__(256) void k_final(const u16* __restrict__ h,
                                               const float* __restrict__ W_att, const float* __restrict__ b_att,
                                               const float* __restrict__ W_h1, const float* __restrict__ b_h1,
                                               const float* __restrict__ W_h2, const float* __restrict__ b_h2,
                                               float* __restrict__ anomaly, float* __restrict__ attw, int N) {
  __shared__ float sh[4][512];
  int wave = threadIdx.x >> 6, lane = threadIdx.x & 63;
  int n = blockIdx.x * 4 + wave;
  bool active = (n < N);
  if (active) {
    const u16* row = h + (size_t)n * HCW;
    #pragma unroll
    for (int i = 0; i < 8; i++) sh[wave][i * 64 + lane] = bf2f((u32)row[i * 64 + lane]);
  }
  __syncthreads();
  if (!active) return;
  float acc[8] = {0.f, 0.f, 0.f, 0.f, 0.f, 0.f, 0.f, 0.f};
  #pragma unroll
  for (int i = 0; i < 8; i++) {
    int k = i * 64 + lane;
    float hv = sh[wave][k];
    #pragma unroll
    for (int j = 0; j < 8; j++) acc[j] += hv * W_att[k * 8 + j];
  }
  #pragma unroll
  for (int j = 0; j < 8; j++) {
    #pragma unroll
    for (int m = 1; m < 64; m <<= 1) acc[j] += __shfl_xor(acc[j], m);
    acc[j] += b_att[j];
  }
  float mx = acc[0];
  #pragma unroll
  for (int j = 1; j < 8; j++) mx = fmaxf(mx, acc[j]);
  float sum = 0.f;
  float ex[8];
  #pragma unroll
  for (int j = 0; j < 8; j++) { ex[j] = __expf(acc[j] - mx); sum += ex[j]; }
  if (lane < 8) attw[(size_t)n * 8 + lane] = ex[lane] / sum;
  float tacc = b_h1[lane];
  for (int k = 0; k < 512; k++) tacc += sh[wave][k] * W_h1[k * 64 + lane];
  tacc = fmaxf(tacc, 0.f);
  float p = tacc * W_h2[lane];
  #pragma unroll
  for (int m = 1; m < 64; m <<= 1) p += __shfl_xor(p, m);
  if (lane == 0) anomaly[n] = 1.f / (1.f + __expf(-(p + b_h2[0])));
}

extern "C" void kernel_launch(void* const* d_in, const int* in_sizes, int n_in,
                              void* d_out, int out_size, void* d_ws, size_t ws_size,
                              hipStream_t stream) {
  const float* x       = (const float*)d_in[0];
  const int*   ei      = (const int*)d_in[1];
  const float* W_in    = (const float*)d_in[2];
  const float* b_in    = (const float*)d_in[3];
  const float* W_gat   = (const float*)d_in[4];
  const float* att_src = (const float*)d_in[5];
  const float* att_dst = (const float*)d_in[6];
  const float* b_gat   = (const float*)d_in[7];
  const float* W_att   = (const float*)d_in[8];
  const float* b_att   = (const float*)d_in[9];
  const float* W_h1    = (const float*)d_in[10];
  const float* b_h1    = (const float*)d_in[11];
  const float* W_h2    = (const float*)d_in[12];
  const float* b_h2    = (const float*)d_in[13];

  const int N  = in_sizes[0] / 32;   // 30000
  const int E  = in_sizes[1] / 2;    // 480000
  const int ET = E + N;              // with self-loops

  char* ws = (char*)d_ws;
  size_t off = 0;
  auto alloc = [&](size_t bytes) -> void* {
    void* p = ws + off;
    off = (off + bytes + 255) & ~(size_t)255;
    return p;
  };
  u16* h     = (u16*)alloc((size_t)N * HCW * 2);
  u16* hp    = (u16*)alloc((size_t)N * HCW * 2);
  u16* Wt    = (u16*)alloc((size_t)3 * HCW * HCW * 2);
  float* exb = (float*)alloc((size_t)ET * NHD * 4);
  float* sarr = (float*)alloc((size_t)N * NHD * 4);
  float* darr = (float*)alloc((size_t)N * NHD * 4);
  float* den  = (float*)alloc((size_t)N * NHD * 4);
  int* deg    = (int*)alloc((size_t)N * 4);
  int* ptr    = (int*)alloc((size_t)(N + 1) * 4);
  int* cnt    = (int*)alloc((size_t)N * 4);
  int* csr    = (int*)alloc((size_t)ET * 4);
  int* bsum   = (int*)alloc((size_t)1024 * 4);
  int* boff   = (int*)alloc((size_t)1024 * 4);

  float* anomaly = (float*)d_out;
  float* attw    = (float*)d_out + N;

  hipMemsetAsync(deg, 0, (size_t)N * 4, stream);
  hipMemsetAsync(cnt, 0, (size_t)N * 4, stream);

  int gbE = (ET + 255) / 256;
  int nb  = (N + 255) / 256;
  k_hist<<<gbE, 256, 0, stream>>>(ei, deg, E, N);
  k_scan1<<<nb, 256, 0, stream>>>(deg, ptr, bsum, N);
  k_scan2<<<1, 256, 0, stream>>>(bsum, boff, nb);
  k_scan3<<<nb, 256, 0, stream>>>(ptr, boff, N);
  k_fill<<<gbE, 256, 0, stream>>>(ei, ptr, cnt, csr, E, N);

  k_wconv<<<dim3(16, 16, 3), 256, 0, stream>>>(W_gat, Wt);
  k_inproj<<<N * 2, 256, 0, stream>>>(x, W_in, b_in, h, N);

  dim3 ggrid(HCW / 128, (N + 127) / 128);
  for (int l = 0; l < 3; l++) {
    k_gemm_mfma<<<ggrid, 256, 0, stream>>>(h, Wt + (size_t)l * HCW * HCW, hp, N);
    k_sd<<<(N + 3) / 4, 256, 0, stream>>>(hp, att_src + (size_t)l * NHD * CCH,
                                          att_dst + (size_t)l * NHD * CCH, sarr, darr, N);
    k_softmax<<<N, 64, 0, stream>>>(ptr, csr, sarr, darr, exb, den);
    k_agg<<<N, 256, 0, stream>>>(ptr, csr, hp, exb, den, b_gat + (size_t)l * HCW, h);
  }

  k_final<<<(N + 3) / 4, 256, 0, stream>>>(h, W_att, b_att, W_h1, b_h1, W_h2, b_h2,
                                           anomaly, attw, N);
}